// Round 12
// baseline (589.068 us; speedup 1.0000x reference)
//
#include <hip/hip_runtime.h>

#define E_ 8
#define H_ 1024
#define I_ 2816
#define GU_ 5632
#define T_ 8192
#define NBR_ 2048  // router blocks = T_/4

typedef __attribute__((ext_vector_type(8))) __bf16 bf16x8;
typedef __attribute__((ext_vector_type(4))) float f32x4;
typedef __attribute__((ext_vector_type(8))) unsigned short u16x8;
typedef __attribute__((ext_vector_type(4))) unsigned short u16x4;
typedef unsigned short u16;

__device__ __forceinline__ float bf2f(u16 u) {
  union { unsigned int i; float f; } v; v.i = ((unsigned int)u) << 16; return v.f;
}
__device__ __forceinline__ u16 f2bf(float f) {
  union { float f; unsigned int i; } v; v.f = f;
  unsigned int r = v.i + 0x7fffu + ((v.i >> 16) & 1u);
  return (u16)(r >> 16);
}
__device__ __forceinline__ void gld16(const void* g, void* l) {
  __builtin_amdgcn_global_load_lds((const __attribute__((address_space(1))) void*)g,
                                   (__attribute__((address_space(3))) void*)l, 16, 0, 0);
}

#define BAR() __builtin_amdgcn_s_barrier()
#define VMC(n) asm volatile("s_waitcnt vmcnt(" #n ")" ::: "memory")

// ---------------- router ----------------
__global__ __launch_bounds__(256) void k_router(
    const float* __restrict__ x, const float* __restrict__ gw,
    float* __restrict__ part_imp, int* __restrict__ part_cnt,
    int* __restrict__ tok_e, float* __restrict__ tok_w,
    u16* __restrict__ xb)
{
  __shared__ float s_imp[8];
  __shared__ int s_cnt[8];
  if (threadIdx.x < 8) { s_imp[threadIdx.x] = 0.f; s_cnt[threadIdx.x] = 0; }
  __syncthreads();

  const int t = blockIdx.x * 4 + (threadIdx.x >> 6);
  const int lane = threadIdx.x & 63;
  const float* xr = x + (size_t)t * H_;
  const f32x4* xp = (const f32x4*)(xr + lane * 16);
  f32x4 v0 = xp[0], v1 = xp[1], v2 = xp[2], v3 = xp[3];
  float xv[16];
#pragma unroll
  for (int b = 0; b < 4; ++b) { xv[b] = v0[b]; xv[4+b] = v1[b]; xv[8+b] = v2[b]; xv[12+b] = v3[b]; }
  u16x8 o0, o1;
#pragma unroll
  for (int j = 0; j < 8; ++j) { o0[j] = f2bf(xv[j]); o1[j] = f2bf(xv[8 + j]); }
  *(u16x8*)(xb + (size_t)t * H_ + lane * 16) = o0;
  *(u16x8*)(xb + (size_t)t * H_ + lane * 16 + 8) = o1;

  float lg[8];
#pragma unroll
  for (int e = 0; e < 8; ++e) {
    const f32x4* gp = (const f32x4*)(gw + e * H_ + lane * 16);
    float s = 0.f;
#pragma unroll
    for (int a = 0; a < 4; ++a) {
      f32x4 g4 = gp[a];
#pragma unroll
      for (int b = 0; b < 4; ++b) s += xv[a * 4 + b] * g4[b];
    }
    lg[e] = s;
  }
#pragma unroll
  for (int e = 0; e < 8; ++e)
#pragma unroll
    for (int off = 32; off; off >>= 1) lg[e] += __shfl_xor(lg[e], off);

  float m = lg[0];
#pragma unroll
  for (int e = 1; e < 8; ++e) m = fmaxf(m, lg[e]);
  float p[8], sum = 0.f;
#pragma unroll
  for (int e = 0; e < 8; ++e) { p[e] = __expf(lg[e] - m); sum += p[e]; }
  float inv = 1.f / sum;
#pragma unroll
  for (int e = 0; e < 8; ++e) p[e] *= inv;
  int e0 = 0;
#pragma unroll
  for (int e = 1; e < 8; ++e) if (p[e] > p[e0]) e0 = e;
  int e1 = (e0 == 0) ? 1 : 0;
#pragma unroll
  for (int e = 0; e < 8; ++e) if (e != e0 && p[e] > p[e1]) e1 = e;
  float d = 1.f / (p[e0] + p[e1]);
  if (lane == 0) {
#pragma unroll
    for (int e = 0; e < 8; ++e) atomicAdd(&s_imp[e], p[e]);
    atomicAdd(&s_cnt[e0], 1);
    atomicAdd(&s_cnt[e1], 1);
    tok_e[2 * t] = e0; tok_e[2 * t + 1] = e1;
    tok_w[2 * t] = p[e0] * d; tok_w[2 * t + 1] = p[e1] * d;
  }
  __syncthreads();
  if (threadIdx.x < 8) {
    part_imp[blockIdx.x * 8 + threadIdx.x] = s_imp[threadIdx.x];
    part_cnt[blockIdx.x * 8 + threadIdx.x] = s_cnt[threadIdx.x];
  }
}

// ---------------- reduce partials + offsets + aux loss ----------------
__global__ __launch_bounds__(512) void k_reduce_scan(
    const float* __restrict__ part_imp, const int* __restrict__ part_cnt,
    int* __restrict__ counts, int* __restrict__ offsets, float* __restrict__ out)
{
  const int w = threadIdx.x >> 6, lane = threadIdx.x & 63;
  float si = 0.f; int sc = 0;
  for (int b = lane; b < NBR_; b += 64) { si += part_imp[b * 8 + w]; sc += part_cnt[b * 8 + w]; }
#pragma unroll
  for (int off = 32; off; off >>= 1) { si += __shfl_xor(si, off); sc += __shfl_xor(sc, off); }
  __shared__ float fimp[8];
  __shared__ int fcnt[8];
  if (lane == 0) { fimp[w] = si; fcnt[w] = sc; }
  __syncthreads();
  if (threadIdx.x == 0) {
    int off = 0; float aux = 0.f;
#pragma unroll
    for (int e = 0; e < 8; ++e) {
      counts[e] = fcnt[e]; offsets[e] = off; off += fcnt[e];
      aux += fimp[e] * (float)fcnt[e];
    }
    out[(size_t)T_ * H_] = 8.f * aux / ((float)T_ * (float)(2 * T_));
  }
}

// ---------------- scatter (block-aggregated) ----------------
__global__ __launch_bounds__(256) void k_scatter(
    const int* __restrict__ tok_e, const float* __restrict__ tok_w,
    const int* __restrict__ offsets, int* __restrict__ cursors,
    int* __restrict__ rows, float* __restrict__ wslot)
{
  __shared__ int lcnt[8], lbase[8];
  if (threadIdx.x < 8) lcnt[threadIdx.x] = 0;
  __syncthreads();
  const int t = blockIdx.x * 256 + threadIdx.x;
  const int e0 = tok_e[2 * t], e1 = tok_e[2 * t + 1];
  const int p0 = atomicAdd(&lcnt[e0], 1);
  const int p1 = atomicAdd(&lcnt[e1], 1);
  __syncthreads();
  if (threadIdx.x < 8) lbase[threadIdx.x] = atomicAdd(&cursors[threadIdx.x], lcnt[threadIdx.x]);
  __syncthreads();
  const int s0 = offsets[e0] + lbase[e0] + p0;
  const int s1 = offsets[e1] + lbase[e1] + p1;
  rows[s0] = t; wslot[s0] = tok_w[2 * t];
  rows[s1] = t; wslot[s1] = tok_w[2 * t + 1];
}

// ---------------- transpose+convert: src[z][R][C] f32 -> dst[z][C][R] bf16, 64x64 ----------------
__global__ __launch_bounds__(256) void k_transpose(
    const float* __restrict__ src, u16* __restrict__ dst, int R, int C)
{
  __shared__ float tile[64][68];
  const int z = blockIdx.z;
  const int c0 = blockIdx.x * 64, r0 = blockIdx.y * 64;
  const float* s = src + (size_t)z * R * C;
  u16* d = dst + (size_t)z * R * C;
  const int tx = threadIdx.x & 15, ty = threadIdx.x >> 4;
#pragma unroll
  for (int i = 0; i < 4; ++i) {
    f32x4 v = *(const f32x4*)(s + (size_t)(r0 + ty + i * 16) * C + c0 + tx * 4);
    *(f32x4*)(&tile[ty + i * 16][tx * 4]) = v;
  }
  __syncthreads();
  const int c = threadIdx.x >> 2, rq = threadIdx.x & 3;
#pragma unroll
  for (int j = 0; j < 4; ++j) {
    u16x4 w;
#pragma unroll
    for (int m = 0; m < 4; ++m) w[m] = f2bf(tile[rq * 16 + j * 4 + m][c]);
    *(u16x4*)(&d[(size_t)(c0 + c) * R + r0 + rq * 16 + j * 4]) = w;
  }
}

// ============ GEMM1: 256 rows x (128g+128u), BK=64, counted-vmcnt 2-deep ============
__global__ __launch_bounds__(512, 2) void k_gemm1(
    const u16* __restrict__ xb, const u16* __restrict__ wgu_t,
    const int* __restrict__ counts, const int* __restrict__ offsets,
    const int* __restrict__ rows, const float* __restrict__ wslot,
    u16* __restrict__ act)
{
  extern __shared__ char sh[];
  const int bid = blockIdx.x;                 // 5632 blocks: 704/XCD = one expert/XCD
  const int l = (bid & 7) * 704 + (bid >> 3);
  const int e = l / 704;
  const int rm = l - e * 704;
  const int yb = rm >> 5, xx = rm & 31;
  const int cnt = counts[e];
  const int m0 = xx * 256;
  if (m0 >= cnt) return;
  const int seg = offsets[e];
  const int segLast = seg + cnt - 1;
  const int n0 = yb * 128;

  const int tid = threadIdx.x;
  const int wid = tid >> 6, lane = tid & 63;
  const int srow = tid >> 3;
  const int scol = (((tid & 7) ^ (srow & 7)) * 8);

  const u16* wge = wgu_t + (size_t)e * GU_ * H_;

  const u16* aPtr[4];
#pragma unroll
  for (int i = 0; i < 4; ++i) {
    int slot = seg + m0 + i * 64 + srow;
    aPtr[i] = xb + (size_t)rows[slot > segLast ? segLast : slot] * H_ + scol;
  }
  const u16* bPtr[4];
#pragma unroll
  for (int i = 0; i < 4; ++i) {
    int r = i * 64 + srow;
    int gr = (r < 128) ? (n0 + r) : (I_ + n0 + (r - 128));
    bPtr[i] = wge + (size_t)gr * H_ + scol;
  }

  const int wm = (wid >> 2) * 128;
  const int wn = (wid & 3) * 32;

  f32x4 accg[8][2], accu[8][2];
#pragma unroll
  for (int i = 0; i < 8; ++i)
#pragma unroll
    for (int j = 0; j < 2; ++j) { accg[i][j] = (f32x4){0.f,0.f,0.f,0.f}; accu[i][j] = (f32x4){0.f,0.f,0.f,0.f}; }

#define STAGE_A1(b, kt) { const int k0 = (kt) * 64;                               \
    char* dst = sh + (b) * 65536 + tid * 16;                                      \
    _Pragma("unroll") for (int i = 0; i < 4; ++i) gld16(aPtr[i] + k0, dst + i * 8192); }
#define STAGE_B1(b, kt) { const int k0 = (kt) * 64;                               \
    char* dst = sh + (b) * 65536 + 32768 + tid * 16;                              \
    _Pragma("unroll") for (int i = 0; i < 4; ++i) gld16(bPtr[i] + k0, dst + i * 8192); }

  const int NT = H_ / 64;  // 16
  STAGE_A1(0, 0); STAGE_B1(0, 0); STAGE_A1(1, 1);
  VMC(4);
  BAR();

  int cur = 0;
#pragma unroll 2
  for (int t = 0; t < NT; ++t) {
    STAGE_B1(cur ^ 1, (t + 1 < NT) ? t + 1 : NT - 1);
    const u16* As = (const u16*)(sh + cur * 65536);
    const u16* Bs = As + 16384;
#pragma unroll
    for (int ks = 0; ks < 2; ++ks) {
      const int koff = (ks * 32 + (lane >> 4) * 8) ^ ((lane & 7) * 8);
      bf16x8 a[8], bg[2], bu[2];
#pragma unroll
      for (int mf = 0; mf < 8; ++mf)
        a[mf] = *(const bf16x8*)(As + (wm + mf * 16 + (lane & 15)) * 64 + koff);
#pragma unroll
      for (int nf = 0; nf < 2; ++nf) {
        bg[nf] = *(const bf16x8*)(Bs + (wn + nf * 16 + (lane & 15)) * 64 + koff);
        bu[nf] = *(const bf16x8*)(Bs + (128 + wn + nf * 16 + (lane & 15)) * 64 + koff);
      }
      __builtin_amdgcn_s_setprio(1);
#pragma unroll
      for (int mf = 0; mf < 8; ++mf)
#pragma unroll
        for (int nf = 0; nf < 2; ++nf) {
          accg[mf][nf] = __builtin_amdgcn_mfma_f32_16x16x32_bf16(a[mf], bg[nf], accg[mf][nf], 0, 0, 0);
          accu[mf][nf] = __builtin_amdgcn_mfma_f32_16x16x32_bf16(a[mf], bu[nf], accu[mf][nf], 0, 0, 0);
        }
      __builtin_amdgcn_s_setprio(0);
    }
    asm volatile("" ::: "memory");
    BAR();
    STAGE_A1(cur, (t + 2 < NT) ? t + 2 : NT - 1);
    VMC(4);
    BAR();
    cur ^= 1;
  }
  VMC(0);
#undef STAGE_A1
#undef STAGE_B1

#pragma unroll
  for (int mf = 0; mf < 8; ++mf)
#pragma unroll
    for (int reg = 0; reg < 4; ++reg) {
      const int r = wm + mf * 16 + (lane >> 4) * 4 + reg;
      if (m0 + r >= cnt) continue;
      const int slot = seg + m0 + r;
      const float w = wslot[slot];
#pragma unroll
      for (int nf = 0; nf < 2; ++nf) {
        float g = accg[mf][nf][reg];
        float u = accu[mf][nf][reg];
        float sv = (g / (1.f + __expf(-g))) * u * w;
        act[(size_t)slot * I_ + n0 + wn + nf * 16 + (lane & 15)] = f2bf(sv);
      }
    }
}

// ============ GEMM2: 256 x 256, BK=64, counted-vmcnt 2-deep, FUSED combine (atomic) ============
__global__ __launch_bounds__(512, 2) void k_gemm2(
    const u16* __restrict__ act, const u16* __restrict__ wd_t,
    const int* __restrict__ counts, const int* __restrict__ offsets,
    const int* __restrict__ rows, float* __restrict__ out)
{
  extern __shared__ char sh[];
  const int bid = blockIdx.x;                 // 1024 blocks: 128/XCD = one expert/XCD
  const int l = (bid & 7) * 128 + (bid >> 3);
  const int e = l >> 7;
  const int rm = l & 127;
  const int yb = rm >> 5, xx = rm & 31;
  const int cnt = counts[e];
  const int m0 = xx * 256;
  if (m0 >= cnt) return;
  const int seg = offsets[e];
  const int segLast = seg + cnt - 1;
  const int n0 = yb * 256;

  const int tid = threadIdx.x;
  const int wid = tid >> 6, lane = tid & 63;
  const int srow = tid >> 3;
  const int scol = (((tid & 7) ^ (srow & 7)) * 8);

  const u16* wde = wd_t + (size_t)e * H_ * I_;

  const u16* aPtr[4];
#pragma unroll
  for (int i = 0; i < 4; ++i) {
    int slot = seg + m0 + i * 64 + srow;
    aPtr[i] = act + (size_t)(slot > segLast ? segLast : slot) * I_ + scol;
  }
  const u16* bPtr[4];
#pragma unroll
  for (int i = 0; i < 4; ++i)
    bPtr[i] = wde + (size_t)(n0 + i * 64 + srow) * I_ + scol;

  const int wm = (wid >> 2) * 128;
  const int wn = (wid & 3) * 64;

  f32x4 acc[8][4];
#pragma unroll
  for (int i = 0; i < 8; ++i)
#pragma unroll
    for (int j = 0; j < 4; ++j) acc[i][j] = (f32x4){0.f,0.f,0.f,0.f};

#define STAGE_A2(b, kt) { const int k0 = (kt) * 64;                               \
    char* dst = sh + (b) * 65536 + tid * 16;                                      \
    _Pragma("unroll") for (int i = 0; i < 4; ++i) gld16(aPtr[i] + k0, dst + i * 8192); }
#define STAGE_B2(b, kt) { const int k0 = (kt) * 64;                               \
    char* dst = sh + (b) * 65536 + 32768 + tid * 16;                              \
    _Pragma("unroll") for (int i = 0; i < 4; ++i) gld16(bPtr[i] + k0, dst + i * 8192); }

  const int NT = I_ / 64;  // 44
  STAGE_A2(0, 0); STAGE_B2(0, 0); STAGE_A2(1, 1);
  VMC(4);
  BAR();

  int cur = 0;
#pragma unroll 2
  for (int t = 0; t < NT; ++t) {
    STAGE_B2(cur ^ 1, (t + 1 < NT) ? t + 1 : NT - 1);
    const u16* As = (const u16*)(sh + cur * 65536);
    const u16* Bs = As + 16384;
#pragma unroll
    for (int ks = 0; ks < 2; ++ks) {
      const int koff = (ks * 32 + (lane >> 4) * 8) ^ ((lane & 7) * 8);
      bf16x8 a[8], b[4];
#pragma unroll
      for (int mf = 0; mf < 8; ++mf)
        a[mf] = *(const bf16x8*)(As + (wm + mf * 16 + (lane & 15)) * 64 + koff);
#pragma unroll
      for (int nf = 0; nf < 4; ++nf)
        b[nf] = *(const bf16x8*)(Bs + (wn + nf * 16 + (lane & 15)) * 64 + koff);
      __builtin_amdgcn_s_setprio(1);
#pragma unroll
      for (int mf = 0; mf < 8; ++mf)
#pragma unroll
        for (int nf = 0; nf < 4; ++nf)
          acc[mf][nf] = __builtin_amdgcn_mfma_f32_16x16x32_bf16(a[mf], b[nf], acc[mf][nf], 0, 0, 0);
      __builtin_amdgcn_s_setprio(0);
    }
    asm volatile("" ::: "memory");
    BAR();
    STAGE_A2(cur, (t + 2 < NT) ? t + 2 : NT - 1);
    VMC(4);
    BAR();
    cur ^= 1;
  }
  VMC(0);
#undef STAGE_A2
#undef STAGE_B2

  // fused combine: out[token][col] += y  (fp32 device-scope atomics, disjoint per slot)
#pragma unroll
  for (int mf = 0; mf < 8; ++mf)
#pragma unroll
    for (int reg = 0; reg < 4; ++reg) {
      const int r = wm + mf * 16 + (lane >> 4) * 4 + reg;
      if (m0 + r >= cnt) continue;
      const int slot = seg + m0 + r;
      const int token = rows[slot];
      float* orow = out + (size_t)token * H_ + n0 + wn + (lane & 15);
#pragma unroll
      for (int nf = 0; nf < 4; ++nf)
        atomicAdd(orow + nf * 16, acc[mf][nf][reg]);
    }
}

extern "C" void kernel_launch(void* const* d_in, const int* in_sizes, int n_in,
                              void* d_out, int out_size, void* d_ws, size_t ws_size,
                              hipStream_t stream)
{
  const float* x   = (const float*)d_in[0];
  const float* gw  = (const float*)d_in[1];
  const float* wgu = (const float*)d_in[2];
  const float* wd  = (const float*)d_in[3];
  float* out = (float*)d_out;
  char* ws = (char*)d_ws;

  const size_t off_wgu_t = 0;
  const size_t off_wd_t  = off_wgu_t + (size_t)E_ * GU_ * H_ * 2;
  const size_t off_xb    = off_wd_t  + (size_t)E_ * H_ * I_ * 2;
  const size_t off_act   = off_xb    + (size_t)T_ * H_ * 2;
  const size_t off_ctrl  = off_act   + (size_t)2 * T_ * I_ * 2;
  const size_t need = off_ctrl + 128 + 4 * 65536;
  if (ws_size < need) return;

  u16* wgu_t = (u16*)(ws + off_wgu_t);
  u16* wd_t  = (u16*)(ws + off_wd_t);
  u16* xb    = (u16*)(ws + off_xb);
  u16* act   = (u16*)(ws + off_act);
  float* part_imp = (float*)(ws + off_act);   // alias: act dead until gemm1
  int*   part_cnt = (int*)(ws + off_act + (size_t)NBR_ * 8 * 4);
  char* ctrl = ws + off_ctrl;
  int*   counts  = (int*)(ctrl + 0);
  int*   cursors = (int*)(ctrl + 32);
  int*   offsets = (int*)(ctrl + 64);
  int*   tok_e   = (int*)(ctrl + 128);
  float* tok_w   = (float*)(ctrl + 128 + 1 * 65536);
  int*   rows    = (int*)(ctrl + 128 + 2 * 65536);
  float* wslot   = (float*)(ctrl + 128 + 3 * 65536);

  static bool attr_done = false;
  if (!attr_done) {
    hipFuncSetAttribute((const void*)k_gemm1, hipFuncAttributeMaxDynamicSharedMemorySize, 131072);
    hipFuncSetAttribute((const void*)k_gemm2, hipFuncAttributeMaxDynamicSharedMemorySize, 131072);
    attr_done = true;
  }

  // zero out (gemm2 accumulates via atomics); aux written later by reduce_scan
  hipMemsetAsync(out, 0, (size_t)out_size * sizeof(float), stream);
  hipMemsetAsync(ctrl, 0, 96, stream);
  hipLaunchKernelGGL(k_transpose, dim3(GU_ / 64, H_ / 64, E_), dim3(256), 0, stream, wgu, wgu_t, H_, GU_);
  hipLaunchKernelGGL(k_transpose, dim3(H_ / 64, I_ / 64, E_), dim3(256), 0, stream, wd, wd_t, I_, H_);
  hipLaunchKernelGGL(k_router, dim3(NBR_), dim3(256), 0, stream, x, gw, part_imp, part_cnt, tok_e, tok_w, xb);
  hipLaunchKernelGGL(k_reduce_scan, dim3(1), dim3(512), 0, stream, part_imp, part_cnt, counts, offsets, out);
  hipLaunchKernelGGL(k_scatter, dim3(T_ / 256), dim3(256), 0, stream, tok_e, tok_w, offsets, cursors, rows, wslot);
  hipLaunchKernelGGL(k_gemm1, dim3(32 * (I_ / 128) * E_), dim3(512), 131072, stream, xb, wgu_t, counts, offsets, rows, wslot, act);
  hipLaunchKernelGGL(k_gemm2, dim3(32 * (H_ / 256) * E_), dim3(512), 131072, stream, act, wd_t, counts, offsets, rows, out);
}

// Round 13
// 539.459 us; speedup vs baseline: 1.0920x; 1.0920x over previous
//
#include <hip/hip_runtime.h>

#define E_ 8
#define H_ 1024
#define I_ 2816
#define GU_ 5632
#define T_ 8192
#define NBR_ 2048  // router blocks = T_/4

typedef __attribute__((ext_vector_type(8))) __bf16 bf16x8;
typedef __attribute__((ext_vector_type(4))) float f32x4;
typedef __attribute__((ext_vector_type(8))) unsigned short u16x8;
typedef __attribute__((ext_vector_type(4))) unsigned short u16x4;
typedef unsigned short u16;

__device__ __forceinline__ float bf2f(u16 u) {
  union { unsigned int i; float f; } v; v.i = ((unsigned int)u) << 16; return v.f;
}
__device__ __forceinline__ u16 f2bf(float f) {
  union { float f; unsigned int i; } v; v.f = f;
  unsigned int r = v.i + 0x7fffu + ((v.i >> 16) & 1u);
  return (u16)(r >> 16);
}
__device__ __forceinline__ void gld16(const void* g, void* l) {
  __builtin_amdgcn_global_load_lds((const __attribute__((address_space(1))) void*)g,
                                   (__attribute__((address_space(3))) void*)l, 16, 0, 0);
}

#define BAR() __builtin_amdgcn_s_barrier()
#define VMC(n) asm volatile("s_waitcnt vmcnt(" #n ")" ::: "memory")

// ---------------- router ----------------
__global__ __launch_bounds__(256) void k_router(
    const float* __restrict__ x, const float* __restrict__ gw,
    float* __restrict__ part_imp, int* __restrict__ part_cnt,
    int* __restrict__ tok_e, float* __restrict__ tok_w,
    u16* __restrict__ xb)
{
  __shared__ float s_imp[8];
  __shared__ int s_cnt[8];
  if (threadIdx.x < 8) { s_imp[threadIdx.x] = 0.f; s_cnt[threadIdx.x] = 0; }
  __syncthreads();

  const int t = blockIdx.x * 4 + (threadIdx.x >> 6);
  const int lane = threadIdx.x & 63;
  const float* xr = x + (size_t)t * H_;
  const f32x4* xp = (const f32x4*)(xr + lane * 16);
  f32x4 v0 = xp[0], v1 = xp[1], v2 = xp[2], v3 = xp[3];
  float xv[16];
#pragma unroll
  for (int b = 0; b < 4; ++b) { xv[b] = v0[b]; xv[4+b] = v1[b]; xv[8+b] = v2[b]; xv[12+b] = v3[b]; }
  u16x8 o0, o1;
#pragma unroll
  for (int j = 0; j < 8; ++j) { o0[j] = f2bf(xv[j]); o1[j] = f2bf(xv[8 + j]); }
  *(u16x8*)(xb + (size_t)t * H_ + lane * 16) = o0;
  *(u16x8*)(xb + (size_t)t * H_ + lane * 16 + 8) = o1;

  float lg[8];
#pragma unroll
  for (int e = 0; e < 8; ++e) {
    const f32x4* gp = (const f32x4*)(gw + e * H_ + lane * 16);
    float s = 0.f;
#pragma unroll
    for (int a = 0; a < 4; ++a) {
      f32x4 g4 = gp[a];
#pragma unroll
      for (int b = 0; b < 4; ++b) s += xv[a * 4 + b] * g4[b];
    }
    lg[e] = s;
  }
#pragma unroll
  for (int e = 0; e < 8; ++e)
#pragma unroll
    for (int off = 32; off; off >>= 1) lg[e] += __shfl_xor(lg[e], off);

  float m = lg[0];
#pragma unroll
  for (int e = 1; e < 8; ++e) m = fmaxf(m, lg[e]);
  float p[8], sum = 0.f;
#pragma unroll
  for (int e = 0; e < 8; ++e) { p[e] = __expf(lg[e] - m); sum += p[e]; }
  float inv = 1.f / sum;
#pragma unroll
  for (int e = 0; e < 8; ++e) p[e] *= inv;
  int e0 = 0;
#pragma unroll
  for (int e = 1; e < 8; ++e) if (p[e] > p[e0]) e0 = e;
  int e1 = (e0 == 0) ? 1 : 0;
#pragma unroll
  for (int e = 0; e < 8; ++e) if (e != e0 && p[e] > p[e1]) e1 = e;
  float d = 1.f / (p[e0] + p[e1]);
  if (lane == 0) {
#pragma unroll
    for (int e = 0; e < 8; ++e) atomicAdd(&s_imp[e], p[e]);
    atomicAdd(&s_cnt[e0], 1);
    atomicAdd(&s_cnt[e1], 1);
    tok_e[2 * t] = e0; tok_e[2 * t + 1] = e1;
    tok_w[2 * t] = p[e0] * d; tok_w[2 * t + 1] = p[e1] * d;
  }
  __syncthreads();
  if (threadIdx.x < 8) {
    part_imp[blockIdx.x * 8 + threadIdx.x] = s_imp[threadIdx.x];
    part_cnt[blockIdx.x * 8 + threadIdx.x] = s_cnt[threadIdx.x];
  }
}

// ---------------- reduce partials + offsets + aux loss ----------------
__global__ __launch_bounds__(512) void k_reduce_scan(
    const float* __restrict__ part_imp, const int* __restrict__ part_cnt,
    int* __restrict__ counts, int* __restrict__ offsets, float* __restrict__ out)
{
  const int w = threadIdx.x >> 6, lane = threadIdx.x & 63;
  float si = 0.f; int sc = 0;
  for (int b = lane; b < NBR_; b += 64) { si += part_imp[b * 8 + w]; sc += part_cnt[b * 8 + w]; }
#pragma unroll
  for (int off = 32; off; off >>= 1) { si += __shfl_xor(si, off); sc += __shfl_xor(sc, off); }
  __shared__ float fimp[8];
  __shared__ int fcnt[8];
  if (lane == 0) { fimp[w] = si; fcnt[w] = sc; }
  __syncthreads();
  if (threadIdx.x == 0) {
    int off = 0; float aux = 0.f;
#pragma unroll
    for (int e = 0; e < 8; ++e) {
      counts[e] = fcnt[e]; offsets[e] = off; off += fcnt[e];
      aux += fimp[e] * (float)fcnt[e];
    }
    out[(size_t)T_ * H_] = 8.f * aux / ((float)T_ * (float)(2 * T_));
  }
}

// ---------------- scatter (block-aggregated) ----------------
__global__ __launch_bounds__(256) void k_scatter(
    const int* __restrict__ tok_e, const float* __restrict__ tok_w,
    const int* __restrict__ offsets, int* __restrict__ cursors,
    int* __restrict__ rows, float* __restrict__ wslot, int* __restrict__ t2s)
{
  __shared__ int lcnt[8], lbase[8];
  if (threadIdx.x < 8) lcnt[threadIdx.x] = 0;
  __syncthreads();
  const int t = blockIdx.x * 256 + threadIdx.x;
  const int e0 = tok_e[2 * t], e1 = tok_e[2 * t + 1];
  const int p0 = atomicAdd(&lcnt[e0], 1);
  const int p1 = atomicAdd(&lcnt[e1], 1);
  __syncthreads();
  if (threadIdx.x < 8) lbase[threadIdx.x] = atomicAdd(&cursors[threadIdx.x], lcnt[threadIdx.x]);
  __syncthreads();
  const int s0 = offsets[e0] + lbase[e0] + p0;
  const int s1 = offsets[e1] + lbase[e1] + p1;
  rows[s0] = t; wslot[s0] = tok_w[2 * t];     t2s[2 * t] = s0;
  rows[s1] = t; wslot[s1] = tok_w[2 * t + 1]; t2s[2 * t + 1] = s1;
}

// ---------------- merged transpose+convert: both weight tensors in one launch ----------------
// tiles 0..11263: wgu [H][GU] -> wgu_t [GU][H]; tiles 11264..16895: wd [I][H] -> wd_t [H][I]
__global__ __launch_bounds__(256) void k_transpose_all(
    const float* __restrict__ wgu, u16* __restrict__ wgu_t,
    const float* __restrict__ wd,  u16* __restrict__ wd_t)
{
  const int bid = blockIdx.x;
  const float* s; u16* d; int R, C, c0, r0;
  if (bid < 11264) {                 // wgu: C=GU (88 tiles), R=H (16 tiles), E=8
    const int z = bid / 1408, rem = bid - z * 1408;
    const int cx = rem % 88, ry = rem / 88;
    R = H_; C = GU_;
    s = wgu + (size_t)z * R * C;  d = wgu_t + (size_t)z * R * C;
    c0 = cx * 64; r0 = ry * 64;
  } else {                           // wd: C=H (16 tiles), R=I (44 tiles), E=8
    const int b2 = bid - 11264;
    const int z = b2 / 704, rem = b2 - z * 704;
    const int cx = rem % 16, ry = rem / 16;
    R = I_; C = H_;
    s = wd + (size_t)z * R * C;  d = wd_t + (size_t)z * R * C;
    c0 = cx * 64; r0 = ry * 64;
  }
  __shared__ float tile[64][68];
  const int tx = threadIdx.x & 15, ty = threadIdx.x >> 4;
#pragma unroll
  for (int i = 0; i < 4; ++i) {
    f32x4 v = *(const f32x4*)(s + (size_t)(r0 + ty + i * 16) * C + c0 + tx * 4);
    *(f32x4*)(&tile[ty + i * 16][tx * 4]) = v;
  }
  __syncthreads();
  const int c = threadIdx.x >> 2, rq = threadIdx.x & 3;
#pragma unroll
  for (int j = 0; j < 4; ++j) {
    u16x4 w;
#pragma unroll
    for (int m = 0; m < 4; ++m) w[m] = f2bf(tile[rq * 16 + j * 4 + m][c]);
    *(u16x4*)(&d[(size_t)(c0 + c) * R + r0 + rq * 16 + j * 4]) = w;
  }
}

// ============ GEMM1: 256 rows x (128g+128u), BK=64, counted-vmcnt 2-deep (round-10 best) ============
__global__ __launch_bounds__(512, 2) void k_gemm1(
    const u16* __restrict__ xb, const u16* __restrict__ wgu_t,
    const int* __restrict__ counts, const int* __restrict__ offsets,
    const int* __restrict__ rows, const float* __restrict__ wslot,
    u16* __restrict__ act)
{
  extern __shared__ char sh[];
  const int bid = blockIdx.x;                 // 5632 blocks: 704/XCD = one expert/XCD
  const int l = (bid & 7) * 704 + (bid >> 3);
  const int e = l / 704;
  const int rm = l - e * 704;
  const int yb = rm >> 5, xx = rm & 31;
  const int cnt = counts[e];
  const int m0 = xx * 256;
  if (m0 >= cnt) return;
  const int seg = offsets[e];
  const int segLast = seg + cnt - 1;
  const int n0 = yb * 128;

  const int tid = threadIdx.x;
  const int wid = tid >> 6, lane = tid & 63;
  const int srow = tid >> 3;
  const int scol = (((tid & 7) ^ (srow & 7)) * 8);

  const u16* wge = wgu_t + (size_t)e * GU_ * H_;

  const u16* aPtr[4];
#pragma unroll
  for (int i = 0; i < 4; ++i) {
    int slot = seg + m0 + i * 64 + srow;
    aPtr[i] = xb + (size_t)rows[slot > segLast ? segLast : slot] * H_ + scol;
  }
  const u16* bPtr[4];
#pragma unroll
  for (int i = 0; i < 4; ++i) {
    int r = i * 64 + srow;
    int gr = (r < 128) ? (n0 + r) : (I_ + n0 + (r - 128));
    bPtr[i] = wge + (size_t)gr * H_ + scol;
  }

  const int wm = (wid >> 2) * 128;
  const int wn = (wid & 3) * 32;

  f32x4 accg[8][2], accu[8][2];
#pragma unroll
  for (int i = 0; i < 8; ++i)
#pragma unroll
    for (int j = 0; j < 2; ++j) { accg[i][j] = (f32x4){0.f,0.f,0.f,0.f}; accu[i][j] = (f32x4){0.f,0.f,0.f,0.f}; }

#define STAGE_A1(b, kt) { const int k0 = (kt) * 64;                               \
    char* dst = sh + (b) * 65536 + tid * 16;                                      \
    _Pragma("unroll") for (int i = 0; i < 4; ++i) gld16(aPtr[i] + k0, dst + i * 8192); }
#define STAGE_B1(b, kt) { const int k0 = (kt) * 64;                               \
    char* dst = sh + (b) * 65536 + 32768 + tid * 16;                              \
    _Pragma("unroll") for (int i = 0; i < 4; ++i) gld16(bPtr[i] + k0, dst + i * 8192); }

  const int NT = H_ / 64;  // 16
  STAGE_A1(0, 0); STAGE_B1(0, 0); STAGE_A1(1, 1);
  VMC(4);
  BAR();

  int cur = 0;
#pragma unroll 2
  for (int t = 0; t < NT; ++t) {
    STAGE_B1(cur ^ 1, (t + 1 < NT) ? t + 1 : NT - 1);
    const u16* As = (const u16*)(sh + cur * 65536);
    const u16* Bs = As + 16384;
#pragma unroll
    for (int ks = 0; ks < 2; ++ks) {
      const int koff = (ks * 32 + (lane >> 4) * 8) ^ ((lane & 7) * 8);
      bf16x8 a[8], bg[2], bu[2];
#pragma unroll
      for (int mf = 0; mf < 8; ++mf)
        a[mf] = *(const bf16x8*)(As + (wm + mf * 16 + (lane & 15)) * 64 + koff);
#pragma unroll
      for (int nf = 0; nf < 2; ++nf) {
        bg[nf] = *(const bf16x8*)(Bs + (wn + nf * 16 + (lane & 15)) * 64 + koff);
        bu[nf] = *(const bf16x8*)(Bs + (128 + wn + nf * 16 + (lane & 15)) * 64 + koff);
      }
      __builtin_amdgcn_s_setprio(1);
#pragma unroll
      for (int mf = 0; mf < 8; ++mf)
#pragma unroll
        for (int nf = 0; nf < 2; ++nf) {
          accg[mf][nf] = __builtin_amdgcn_mfma_f32_16x16x32_bf16(a[mf], bg[nf], accg[mf][nf], 0, 0, 0);
          accu[mf][nf] = __builtin_amdgcn_mfma_f32_16x16x32_bf16(a[mf], bu[nf], accu[mf][nf], 0, 0, 0);
        }
      __builtin_amdgcn_s_setprio(0);
    }
    asm volatile("" ::: "memory");
    BAR();
    STAGE_A1(cur, (t + 2 < NT) ? t + 2 : NT - 1);
    VMC(4);
    BAR();
    cur ^= 1;
  }
  VMC(0);
#undef STAGE_A1
#undef STAGE_B1

#pragma unroll
  for (int mf = 0; mf < 8; ++mf)
#pragma unroll
    for (int reg = 0; reg < 4; ++reg) {
      const int r = wm + mf * 16 + (lane >> 4) * 4 + reg;
      if (m0 + r >= cnt) continue;
      const int slot = seg + m0 + r;
      const float w = wslot[slot];
#pragma unroll
      for (int nf = 0; nf < 2; ++nf) {
        float g = accg[mf][nf][reg];
        float u = accu[mf][nf][reg];
        float sv = (g / (1.f + __expf(-g))) * u * w;
        act[(size_t)slot * I_ + n0 + wn + nf * 16 + (lane & 15)] = f2bf(sv);
      }
    }
}

// ============ GEMM2: 256 x 256, BK=64, counted-vmcnt 2-deep (round-10 best) ============
__global__ __launch_bounds__(512, 2) void k_gemm2(
    const u16* __restrict__ act, const u16* __restrict__ wd_t,
    const int* __restrict__ counts, const int* __restrict__ offsets,
    u16* __restrict__ y)
{
  extern __shared__ char sh[];
  const int bid = blockIdx.x;                 // 1024 blocks: 128/XCD = one expert/XCD
  const int l = (bid & 7) * 128 + (bid >> 3);
  const int e = l >> 7;
  const int rm = l & 127;
  const int yb = rm >> 5, xx = rm & 31;
  const int cnt = counts[e];
  const int m0 = xx * 256;
  if (m0 >= cnt) return;
  const int seg = offsets[e];
  const int segLast = seg + cnt - 1;
  const int n0 = yb * 256;

  const int tid = threadIdx.x;
  const int wid = tid >> 6, lane = tid & 63;
  const int srow = tid >> 3;
  const int scol = (((tid & 7) ^ (srow & 7)) * 8);

  const u16* wde = wd_t + (size_t)e * H_ * I_;

  const u16* aPtr[4];
#pragma unroll
  for (int i = 0; i < 4; ++i) {
    int slot = seg + m0 + i * 64 + srow;
    aPtr[i] = act + (size_t)(slot > segLast ? segLast : slot) * I_ + scol;
  }
  const u16* bPtr[4];
#pragma unroll
  for (int i = 0; i < 4; ++i)
    bPtr[i] = wde + (size_t)(n0 + i * 64 + srow) * I_ + scol;

  const int wm = (wid >> 2) * 128;
  const int wn = (wid & 3) * 64;

  f32x4 acc[8][4];
#pragma unroll
  for (int i = 0; i < 8; ++i)
#pragma unroll
    for (int j = 0; j < 4; ++j) acc[i][j] = (f32x4){0.f,0.f,0.f,0.f};

#define STAGE_A2(b, kt) { const int k0 = (kt) * 64;                               \
    char* dst = sh + (b) * 65536 + tid * 16;                                      \
    _Pragma("unroll") for (int i = 0; i < 4; ++i) gld16(aPtr[i] + k0, dst + i * 8192); }
#define STAGE_B2(b, kt) { const int k0 = (kt) * 64;                               \
    char* dst = sh + (b) * 65536 + 32768 + tid * 16;                              \
    _Pragma("unroll") for (int i = 0; i < 4; ++i) gld16(bPtr[i] + k0, dst + i * 8192); }

  const int NT = I_ / 64;  // 44
  STAGE_A2(0, 0); STAGE_B2(0, 0); STAGE_A2(1, 1);
  VMC(4);
  BAR();

  int cur = 0;
#pragma unroll 2
  for (int t = 0; t < NT; ++t) {
    STAGE_B2(cur ^ 1, (t + 1 < NT) ? t + 1 : NT - 1);
    const u16* As = (const u16*)(sh + cur * 65536);
    const u16* Bs = As + 16384;
#pragma unroll
    for (int ks = 0; ks < 2; ++ks) {
      const int koff = (ks * 32 + (lane >> 4) * 8) ^ ((lane & 7) * 8);
      bf16x8 a[8], b[4];
#pragma unroll
      for (int mf = 0; mf < 8; ++mf)
        a[mf] = *(const bf16x8*)(As + (wm + mf * 16 + (lane & 15)) * 64 + koff);
#pragma unroll
      for (int nf = 0; nf < 4; ++nf)
        b[nf] = *(const bf16x8*)(Bs + (wn + nf * 16 + (lane & 15)) * 64 + koff);
      __builtin_amdgcn_s_setprio(1);
#pragma unroll
      for (int mf = 0; mf < 8; ++mf)
#pragma unroll
        for (int nf = 0; nf < 4; ++nf)
          acc[mf][nf] = __builtin_amdgcn_mfma_f32_16x16x32_bf16(a[mf], b[nf], acc[mf][nf], 0, 0, 0);
      __builtin_amdgcn_s_setprio(0);
    }
    asm volatile("" ::: "memory");
    BAR();
    STAGE_A2(cur, (t + 2 < NT) ? t + 2 : NT - 1);
    VMC(4);
    BAR();
    cur ^= 1;
  }
  VMC(0);
#undef STAGE_A2
#undef STAGE_B2

#pragma unroll
  for (int mf = 0; mf < 8; ++mf)
#pragma unroll
    for (int reg = 0; reg < 4; ++reg) {
      const int r = wm + mf * 16 + (lane >> 4) * 4 + reg;
      if (m0 + r >= cnt) continue;
      const int slot = seg + m0 + r;
#pragma unroll
      for (int nf = 0; nf < 4; ++nf)
        y[(size_t)slot * H_ + n0 + wn + nf * 16 + (lane & 15)] = f2bf(acc[mf][nf][reg]);
    }
}

// ---------------- combine ----------------
__global__ __launch_bounds__(256) void k_combine(
    const u16* __restrict__ y, const int* __restrict__ t2s, float* __restrict__ out)
{
  const size_t idx = ((size_t)blockIdx.x * 256 + threadIdx.x) * 8;
  const int t = (int)(idx >> 10);
  const int h = (int)(idx & 1023);
  const int s0 = t2s[2 * t], s1 = t2s[2 * t + 1];
  u16x8 a = *(const u16x8*)(y + (size_t)s0 * H_ + h);
  u16x8 b = *(const u16x8*)(y + (size_t)s1 * H_ + h);
  f32x4 o0, o1;
#pragma unroll
  for (int j = 0; j < 4; ++j) o0[j] = bf2f(a[j]) + bf2f(b[j]);
#pragma unroll
  for (int j = 0; j < 4; ++j) o1[j] = bf2f(a[4 + j]) + bf2f(b[4 + j]);
  *(f32x4*)(out + idx) = o0;
  *(f32x4*)(out + idx + 4) = o1;
}

extern "C" void kernel_launch(void* const* d_in, const int* in_sizes, int n_in,
                              void* d_out, int out_size, void* d_ws, size_t ws_size,
                              hipStream_t stream)
{
  const float* x   = (const float*)d_in[0];
  const float* gw  = (const float*)d_in[1];
  const float* wgu = (const float*)d_in[2];
  const float* wd  = (const float*)d_in[3];
  float* out = (float*)d_out;
  char* ws = (char*)d_ws;

  const size_t off_wgu_t = 0;
  const size_t off_wd_t  = off_wgu_t + (size_t)E_ * GU_ * H_ * 2;
  const size_t off_xb    = off_wd_t  + (size_t)E_ * H_ * I_ * 2;
  const size_t off_act   = off_xb    + (size_t)T_ * H_ * 2;
  const size_t off_ctrl  = off_act   + (size_t)2 * T_ * I_ * 2;
  const size_t need = off_ctrl + 128 + 5 * 65536;
  if (ws_size < need) return;

  u16* wgu_t = (u16*)(ws + off_wgu_t);
  u16* wd_t  = (u16*)(ws + off_wd_t);
  u16* xb    = (u16*)(ws + off_xb);
  u16* act   = (u16*)(ws + off_act);
  u16* y     = (u16*)(ws + off_wgu_t);        // alias: wgu_t dead after gemm1
  float* part_imp = (float*)(ws + off_act);   // alias: act dead until gemm1
  int*   part_cnt = (int*)(ws + off_act + (size_t)NBR_ * 8 * 4);
  char* ctrl = ws + off_ctrl;
  int*   counts  = (int*)(ctrl + 0);
  int*   cursors = (int*)(ctrl + 32);
  int*   offsets = (int*)(ctrl + 64);
  int*   tok_e   = (int*)(ctrl + 128);
  float* tok_w   = (float*)(ctrl + 128 + 1 * 65536);
  int*   rows    = (int*)(ctrl + 128 + 2 * 65536);
  float* wslot   = (float*)(ctrl + 128 + 3 * 65536);
  int*   t2s     = (int*)(ctrl + 128 + 4 * 65536);

  static bool attr_done = false;
  if (!attr_done) {
    hipFuncSetAttribute((const void*)k_gemm1, hipFuncAttributeMaxDynamicSharedMemorySize, 131072);
    hipFuncSetAttribute((const void*)k_gemm2, hipFuncAttributeMaxDynamicSharedMemorySize, 131072);
    attr_done = true;
  }

  hipMemsetAsync(ctrl, 0, 96, stream);
  hipLaunchKernelGGL(k_transpose_all, dim3(11264 + 5632), dim3(256), 0, stream, wgu, wgu_t, wd, wd_t);
  hipLaunchKernelGGL(k_router, dim3(NBR_), dim3(256), 0, stream, x, gw, part_imp, part_cnt, tok_e, tok_w, xb);
  hipLaunchKernelGGL(k_reduce_scan, dim3(1), dim3(512), 0, stream, part_imp, part_cnt, counts, offsets, out);
  hipLaunchKernelGGL(k_scatter, dim3(T_ / 256), dim3(256), 0, stream, tok_e, tok_w, offsets, cursors, rows, wslot, t2s);
  hipLaunchKernelGGL(k_gemm1, dim3(32 * (I_ / 128) * E_), dim3(512), 131072, stream, xb, wgu_t, counts, offsets, rows, wslot, act);
  hipLaunchKernelGGL(k_gemm2, dim3(32 * (H_ / 256) * E_), dim3(512), 131072, stream, act, wd_t, counts, offsets, y);
  hipLaunchKernelGGL(k_combine, dim3((T_ * H_) / (256 * 8)), dim3(256), 0, stream, y, t2s, out);
}

// Round 14
// 538.493 us; speedup vs baseline: 1.0939x; 1.0018x over previous
//
#include <hip/hip_runtime.h>

#define E_ 8
#define H_ 1024
#define I_ 2816
#define GU_ 5632
#define T_ 8192
#define NBR_ 2048  // router blocks = T_/4

typedef __attribute__((ext_vector_type(8))) __bf16 bf16x8;
typedef __attribute__((ext_vector_type(4))) float f32x4;
typedef __attribute__((ext_vector_type(8))) unsigned short u16x8;
typedef __attribute__((ext_vector_type(4))) unsigned short u16x4;
typedef unsigned short u16;

__device__ __forceinline__ float bf2f(u16 u) {
  union { unsigned int i; float f; } v; v.i = ((unsigned int)u) << 16; return v.f;
}
__device__ __forceinline__ u16 f2bf(float f) {
  union { float f; unsigned int i; } v; v.f = f;
  unsigned int r = v.i + 0x7fffu + ((v.i >> 16) & 1u);
  return (u16)(r >> 16);
}
__device__ __forceinline__ void gld16(const void* g, void* l) {
  __builtin_amdgcn_global_load_lds((const __attribute__((address_space(1))) void*)g,
                                   (__attribute__((address_space(3))) void*)l, 16, 0, 0);
}

#define BAR() __builtin_amdgcn_s_barrier()
#define VMC(n) asm volatile("s_waitcnt vmcnt(" #n ")" ::: "memory")

// ---------------- router ----------------
__global__ __launch_bounds__(256) void k_router(
    const float* __restrict__ x, const float* __restrict__ gw,
    float* __restrict__ part_imp, int* __restrict__ part_cnt,
    int* __restrict__ tok_e, float* __restrict__ tok_w,
    u16* __restrict__ xb)
{
  __shared__ float s_imp[8];
  __shared__ int s_cnt[8];
  if (threadIdx.x < 8) { s_imp[threadIdx.x] = 0.f; s_cnt[threadIdx.x] = 0; }
  __syncthreads();

  const int t = blockIdx.x * 4 + (threadIdx.x >> 6);
  const int lane = threadIdx.x & 63;
  const float* xr = x + (size_t)t * H_;
  const f32x4* xp = (const f32x4*)(xr + lane * 16);
  f32x4 v0 = xp[0], v1 = xp[1], v2 = xp[2], v3 = xp[3];
  float xv[16];
#pragma unroll
  for (int b = 0; b < 4; ++b) { xv[b] = v0[b]; xv[4+b] = v1[b]; xv[8+b] = v2[b]; xv[12+b] = v3[b]; }
  u16x8 o0, o1;
#pragma unroll
  for (int j = 0; j < 8; ++j) { o0[j] = f2bf(xv[j]); o1[j] = f2bf(xv[8 + j]); }
  *(u16x8*)(xb + (size_t)t * H_ + lane * 16) = o0;
  *(u16x8*)(xb + (size_t)t * H_ + lane * 16 + 8) = o1;

  float lg[8];
#pragma unroll
  for (int e = 0; e < 8; ++e) {
    const f32x4* gp = (const f32x4*)(gw + e * H_ + lane * 16);
    float s = 0.f;
#pragma unroll
    for (int a = 0; a < 4; ++a) {
      f32x4 g4 = gp[a];
#pragma unroll
      for (int b = 0; b < 4; ++b) s += xv[a * 4 + b] * g4[b];
    }
    lg[e] = s;
  }
#pragma unroll
  for (int e = 0; e < 8; ++e)
#pragma unroll
    for (int off = 32; off; off >>= 1) lg[e] += __shfl_xor(lg[e], off);

  float m = lg[0];
#pragma unroll
  for (int e = 1; e < 8; ++e) m = fmaxf(m, lg[e]);
  float p[8], sum = 0.f;
#pragma unroll
  for (int e = 0; e < 8; ++e) { p[e] = __expf(lg[e] - m); sum += p[e]; }
  float inv = 1.f / sum;
#pragma unroll
  for (int e = 0; e < 8; ++e) p[e] *= inv;
  int e0 = 0;
#pragma unroll
  for (int e = 1; e < 8; ++e) if (p[e] > p[e0]) e0 = e;
  int e1 = (e0 == 0) ? 1 : 0;
#pragma unroll
  for (int e = 0; e < 8; ++e) if (e != e0 && p[e] > p[e1]) e1 = e;
  float d = 1.f / (p[e0] + p[e1]);
  if (lane == 0) {
#pragma unroll
    for (int e = 0; e < 8; ++e) atomicAdd(&s_imp[e], p[e]);
    atomicAdd(&s_cnt[e0], 1);
    atomicAdd(&s_cnt[e1], 1);
    tok_e[2 * t] = e0; tok_e[2 * t + 1] = e1;
    tok_w[2 * t] = p[e0] * d; tok_w[2 * t + 1] = p[e1] * d;
  }
  __syncthreads();
  if (threadIdx.x < 8) {
    part_imp[blockIdx.x * 8 + threadIdx.x] = s_imp[threadIdx.x];
    part_cnt[blockIdx.x * 8 + threadIdx.x] = s_cnt[threadIdx.x];
  }
}

// ---------------- reduce partials + offsets + aux loss ----------------
__global__ __launch_bounds__(512) void k_reduce_scan(
    const float* __restrict__ part_imp, const int* __restrict__ part_cnt,
    int* __restrict__ counts, int* __restrict__ offsets, float* __restrict__ out)
{
  const int w = threadIdx.x >> 6, lane = threadIdx.x & 63;
  float si = 0.f; int sc = 0;
  for (int b = lane; b < NBR_; b += 64) { si += part_imp[b * 8 + w]; sc += part_cnt[b * 8 + w]; }
#pragma unroll
  for (int off = 32; off; off >>= 1) { si += __shfl_xor(si, off); sc += __shfl_xor(sc, off); }
  __shared__ float fimp[8];
  __shared__ int fcnt[8];
  if (lane == 0) { fimp[w] = si; fcnt[w] = sc; }
  __syncthreads();
  if (threadIdx.x == 0) {
    int off = 0; float aux = 0.f;
#pragma unroll
    for (int e = 0; e < 8; ++e) {
      counts[e] = fcnt[e]; offsets[e] = off; off += fcnt[e];
      aux += fimp[e] * (float)fcnt[e];
    }
    out[(size_t)T_ * H_] = 8.f * aux / ((float)T_ * (float)(2 * T_));
  }
}

// ---------------- scatter (block-aggregated) ----------------
__global__ __launch_bounds__(256) void k_scatter(
    const int* __restrict__ tok_e, const float* __restrict__ tok_w,
    const int* __restrict__ offsets, int* __restrict__ cursors,
    int* __restrict__ rows, float* __restrict__ wslot, int* __restrict__ t2s)
{
  __shared__ int lcnt[8], lbase[8];
  if (threadIdx.x < 8) lcnt[threadIdx.x] = 0;
  __syncthreads();
  const int t = blockIdx.x * 256 + threadIdx.x;
  const int e0 = tok_e[2 * t], e1 = tok_e[2 * t + 1];
  const int p0 = atomicAdd(&lcnt[e0], 1);
  const int p1 = atomicAdd(&lcnt[e1], 1);
  __syncthreads();
  if (threadIdx.x < 8) lbase[threadIdx.x] = atomicAdd(&cursors[threadIdx.x], lcnt[threadIdx.x]);
  __syncthreads();
  const int s0 = offsets[e0] + lbase[e0] + p0;
  const int s1 = offsets[e1] + lbase[e1] + p1;
  rows[s0] = t; wslot[s0] = tok_w[2 * t];     t2s[2 * t] = s0;
  rows[s1] = t; wslot[s1] = tok_w[2 * t + 1]; t2s[2 * t + 1] = s1;
}

// ---------------- merged transpose+convert: both weight tensors, u16x8 coalesced stores ----------------
// tiles 0..11263: wgu [H][GU] -> wgu_t [GU][H]; tiles 11264..16895: wd [I][H] -> wd_t [H][I]
__global__ __launch_bounds__(256) void k_transpose_all(
    const float* __restrict__ wgu, u16* __restrict__ wgu_t,
    const float* __restrict__ wd,  u16* __restrict__ wd_t)
{
  const int bid = blockIdx.x;
  const float* s; u16* d; int R, C, c0, r0;
  if (bid < 11264) {                 // wgu: C=GU (88 tiles), R=H (16 tiles), E=8
    const int z = bid / 1408, rem = bid - z * 1408;
    const int cx = rem % 88, ry = rem / 88;
    R = H_; C = GU_;
    s = wgu + (size_t)z * R * C;  d = wgu_t + (size_t)z * R * C;
    c0 = cx * 64; r0 = ry * 64;
  } else {                           // wd: C=H (16 tiles), R=I (44 tiles), E=8
    const int b2 = bid - 11264;
    const int z = b2 / 704, rem = b2 - z * 704;
    const int cx = rem % 16, ry = rem / 16;
    R = I_; C = H_;
    s = wd + (size_t)z * R * C;  d = wd_t + (size_t)z * R * C;
    c0 = cx * 64; r0 = ry * 64;
  }
  __shared__ float tile[64][68];
  const int tx = threadIdx.x & 15, ty = threadIdx.x >> 4;
#pragma unroll
  for (int i = 0; i < 4; ++i) {
    f32x4 v = *(const f32x4*)(s + (size_t)(r0 + ty + i * 16) * C + c0 + tx * 4);
    *(f32x4*)(&tile[ty + i * 16][tx * 4]) = v;
  }
  __syncthreads();
  // store: lane owns 16 consecutive output elems -> two u16x8 (16B) stores,
  // 4 lanes cover one 128B-contiguous output row segment (coalesced)
  const int c = threadIdx.x >> 2, rq = threadIdx.x & 3;
  u16x8 w0, w1;
#pragma unroll
  for (int m = 0; m < 8; ++m) w0[m] = f2bf(tile[rq * 16 + m][c]);
#pragma unroll
  for (int m = 0; m < 8; ++m) w1[m] = f2bf(tile[rq * 16 + 8 + m][c]);
  u16* drow = d + (size_t)(c0 + c) * R + r0 + rq * 16;
  *(u16x8*)(drow) = w0;
  *(u16x8*)(drow + 8) = w1;
}

// ============ GEMM1: 256 rows x (128g+128u), BK=64, counted-vmcnt 2-deep (best) ============
__global__ __launch_bounds__(512, 2) void k_gemm1(
    const u16* __restrict__ xb, const u16* __restrict__ wgu_t,
    const int* __restrict__ counts, const int* __restrict__ offsets,
    const int* __restrict__ rows, const float* __restrict__ wslot,
    u16* __restrict__ act)
{
  extern __shared__ char sh[];
  const int bid = blockIdx.x;                 // 5632 blocks: 704/XCD = one expert/XCD
  const int l = (bid & 7) * 704 + (bid >> 3);
  const int e = l / 704;
  const int rm = l - e * 704;
  const int yb = rm >> 5, xx = rm & 31;
  const int cnt = counts[e];
  const int m0 = xx * 256;
  if (m0 >= cnt) return;
  const int seg = offsets[e];
  const int segLast = seg + cnt - 1;
  const int n0 = yb * 128;

  const int tid = threadIdx.x;
  const int wid = tid >> 6, lane = tid & 63;
  const int srow = tid >> 3;
  const int scol = (((tid & 7) ^ (srow & 7)) * 8);

  const u16* wge = wgu_t + (size_t)e * GU_ * H_;

  const u16* aPtr[4];
#pragma unroll
  for (int i = 0; i < 4; ++i) {
    int slot = seg + m0 + i * 64 + srow;
    aPtr[i] = xb + (size_t)rows[slot > segLast ? segLast : slot] * H_ + scol;
  }
  const u16* bPtr[4];
#pragma unroll
  for (int i = 0; i < 4; ++i) {
    int r = i * 64 + srow;
    int gr = (r < 128) ? (n0 + r) : (I_ + n0 + (r - 128));
    bPtr[i] = wge + (size_t)gr * H_ + scol;
  }

  const int wm = (wid >> 2) * 128;
  const int wn = (wid & 3) * 32;

  f32x4 accg[8][2], accu[8][2];
#pragma unroll
  for (int i = 0; i < 8; ++i)
#pragma unroll
    for (int j = 0; j < 2; ++j) { accg[i][j] = (f32x4){0.f,0.f,0.f,0.f}; accu[i][j] = (f32x4){0.f,0.f,0.f,0.f}; }

#define STAGE_A1(b, kt) { const int k0 = (kt) * 64;                               \
    char* dst = sh + (b) * 65536 + tid * 16;                                      \
    _Pragma("unroll") for (int i = 0; i < 4; ++i) gld16(aPtr[i] + k0, dst + i * 8192); }
#define STAGE_B1(b, kt) { const int k0 = (kt) * 64;                               \
    char* dst = sh + (b) * 65536 + 32768 + tid * 16;                              \
    _Pragma("unroll") for (int i = 0; i < 4; ++i) gld16(bPtr[i] + k0, dst + i * 8192); }

  const int NT = H_ / 64;  // 16
  STAGE_A1(0, 0); STAGE_B1(0, 0); STAGE_A1(1, 1);
  VMC(4);
  BAR();

  int cur = 0;
#pragma unroll 2
  for (int t = 0; t < NT; ++t) {
    STAGE_B1(cur ^ 1, (t + 1 < NT) ? t + 1 : NT - 1);
    const u16* As = (const u16*)(sh + cur * 65536);
    const u16* Bs = As + 16384;
#pragma unroll
    for (int ks = 0; ks < 2; ++ks) {
      const int koff = (ks * 32 + (lane >> 4) * 8) ^ ((lane & 7) * 8);
      bf16x8 a[8], bg[2], bu[2];
#pragma unroll
      for (int mf = 0; mf < 8; ++mf)
        a[mf] = *(const bf16x8*)(As + (wm + mf * 16 + (lane & 15)) * 64 + koff);
#pragma unroll
      for (int nf = 0; nf < 2; ++nf) {
        bg[nf] = *(const bf16x8*)(Bs + (wn + nf * 16 + (lane & 15)) * 64 + koff);
        bu[nf] = *(const bf16x8*)(Bs + (128 + wn + nf * 16 + (lane & 15)) * 64 + koff);
      }
      __builtin_amdgcn_s_setprio(1);
#pragma unroll
      for (int mf = 0; mf < 8; ++mf)
#pragma unroll
        for (int nf = 0; nf < 2; ++nf) {
          accg[mf][nf] = __builtin_amdgcn_mfma_f32_16x16x32_bf16(a[mf], bg[nf], accg[mf][nf], 0, 0, 0);
          accu[mf][nf] = __builtin_amdgcn_mfma_f32_16x16x32_bf16(a[mf], bu[nf], accu[mf][nf], 0, 0, 0);
        }
      __builtin_amdgcn_s_setprio(0);
    }
    asm volatile("" ::: "memory");
    BAR();
    STAGE_A1(cur, (t + 2 < NT) ? t + 2 : NT - 1);
    VMC(4);
    BAR();
    cur ^= 1;
  }
  VMC(0);
#undef STAGE_A1
#undef STAGE_B1

#pragma unroll
  for (int mf = 0; mf < 8; ++mf)
#pragma unroll
    for (int reg = 0; reg < 4; ++reg) {
      const int r = wm + mf * 16 + (lane >> 4) * 4 + reg;
      if (m0 + r >= cnt) continue;
      const int slot = seg + m0 + r;
      const float w = wslot[slot];
#pragma unroll
      for (int nf = 0; nf < 2; ++nf) {
        float g = accg[mf][nf][reg];
        float u = accu[mf][nf][reg];
        float sv = (g / (1.f + __expf(-g))) * u * w;
        act[(size_t)slot * I_ + n0 + wn + nf * 16 + (lane & 15)] = f2bf(sv);
      }
    }
}

// ============ GEMM2: 256 x 256, BK=64, counted-vmcnt 2-deep (best) ============
__global__ __launch_bounds__(512, 2) void k_gemm2(
    const u16* __restrict__ act, const u16* __restrict__ wd_t,
    const int* __restrict__ counts, const int* __restrict__ offsets,
    u16* __restrict__ y)
{
  extern __shared__ char sh[];
  const int bid = blockIdx.x;                 // 1024 blocks: 128/XCD = one expert/XCD
  const int l = (bid & 7) * 128 + (bid >> 3);
  const int e = l >> 7;
  const int rm = l & 127;
  const int yb = rm >> 5, xx = rm & 31;
  const int cnt = counts[e];
  const int m0 = xx * 256;
  if (m0 >= cnt) return;
  const int seg = offsets[e];
  const int segLast = seg + cnt - 1;
  const int n0 = yb * 256;

  const int tid = threadIdx.x;
  const int wid = tid >> 6, lane = tid & 63;
  const int srow = tid >> 3;
  const int scol = (((tid & 7) ^ (srow & 7)) * 8);

  const u16* wde = wd_t + (size_t)e * H_ * I_;

  const u16* aPtr[4];
#pragma unroll
  for (int i = 0; i < 4; ++i) {
    int slot = seg + m0 + i * 64 + srow;
    aPtr[i] = act + (size_t)(slot > segLast ? segLast : slot) * I_ + scol;
  }
  const u16* bPtr[4];
#pragma unroll
  for (int i = 0; i < 4; ++i)
    bPtr[i] = wde + (size_t)(n0 + i * 64 + srow) * I_ + scol;

  const int wm = (wid >> 2) * 128;
  const int wn = (wid & 3) * 64;

  f32x4 acc[8][4];
#pragma unroll
  for (int i = 0; i < 8; ++i)
#pragma unroll
    for (int j = 0; j < 4; ++j) acc[i][j] = (f32x4){0.f,0.f,0.f,0.f};

#define STAGE_A2(b, kt) { const int k0 = (kt) * 64;                               \
    char* dst = sh + (b) * 65536 + tid * 16;                                      \
    _Pragma("unroll") for (int i = 0; i < 4; ++i) gld16(aPtr[i] + k0, dst + i * 8192); }
#define STAGE_B2(b, kt) { const int k0 = (kt) * 64;                               \
    char* dst = sh + (b) * 65536 + 32768 + tid * 16;                              \
    _Pragma("unroll") for (int i = 0; i < 4; ++i) gld16(bPtr[i] + k0, dst + i * 8192); }

  const int NT = I_ / 64;  // 44
  STAGE_A2(0, 0); STAGE_B2(0, 0); STAGE_A2(1, 1);
  VMC(4);
  BAR();

  int cur = 0;
#pragma unroll 2
  for (int t = 0; t < NT; ++t) {
    STAGE_B2(cur ^ 1, (t + 1 < NT) ? t + 1 : NT - 1);
    const u16* As = (const u16*)(sh + cur * 65536);
    const u16* Bs = As + 16384;
#pragma unroll
    for (int ks = 0; ks < 2; ++ks) {
      const int koff = (ks * 32 + (lane >> 4) * 8) ^ ((lane & 7) * 8);
      bf16x8 a[8], b[4];
#pragma unroll
      for (int mf = 0; mf < 8; ++mf)
        a[mf] = *(const bf16x8*)(As + (wm + mf * 16 + (lane & 15)) * 64 + koff);
#pragma unroll
      for (int nf = 0; nf < 4; ++nf)
        b[nf] = *(const bf16x8*)(Bs + (wn + nf * 16 + (lane & 15)) * 64 + koff);
      __builtin_amdgcn_s_setprio(1);
#pragma unroll
      for (int mf = 0; mf < 8; ++mf)
#pragma unroll
        for (int nf = 0; nf < 4; ++nf)
          acc[mf][nf] = __builtin_amdgcn_mfma_f32_16x16x32_bf16(a[mf], b[nf], acc[mf][nf], 0, 0, 0);
      __builtin_amdgcn_s_setprio(0);
    }
    asm volatile("" ::: "memory");
    BAR();
    STAGE_A2(cur, (t + 2 < NT) ? t + 2 : NT - 1);
    VMC(4);
    BAR();
    cur ^= 1;
  }
  VMC(0);
#undef STAGE_A2
#undef STAGE_B2

#pragma unroll
  for (int mf = 0; mf < 8; ++mf)
#pragma unroll
    for (int reg = 0; reg < 4; ++reg) {
      const int r = wm + mf * 16 + (lane >> 4) * 4 + reg;
      if (m0 + r >= cnt) continue;
      const int slot = seg + m0 + r;
#pragma unroll
      for (int nf = 0; nf < 4; ++nf)
        y[(size_t)slot * H_ + n0 + wn + nf * 16 + (lane & 15)] = f2bf(acc[mf][nf][reg]);
    }
}

// ---------------- combine ----------------
__global__ __launch_bounds__(256) void k_combine(
    const u16* __restrict__ y, const int* __restrict__ t2s, float* __restrict__ out)
{
  const size_t idx = ((size_t)blockIdx.x * 256 + threadIdx.x) * 8;
  const int t = (int)(idx >> 10);
  const int h = (int)(idx & 1023);
  const int s0 = t2s[2 * t], s1 = t2s[2 * t + 1];
  u16x8 a = *(const u16x8*)(y + (size_t)s0 * H_ + h);
  u16x8 b = *(const u16x8*)(y + (size_t)s1 * H_ + h);
  f32x4 o0, o1;
#pragma unroll
  for (int j = 0; j < 4; ++j) o0[j] = bf2f(a[j]) + bf2f(b[j]);
#pragma unroll
  for (int j = 0; j < 4; ++j) o1[j] = bf2f(a[4 + j]) + bf2f(b[4 + j]);
  *(f32x4*)(out + idx) = o0;
  *(f32x4*)(out + idx + 4) = o1;
}

extern "C" void kernel_launch(void* const* d_in, const int* in_sizes, int n_in,
                              void* d_out, int out_size, void* d_ws, size_t ws_size,
                              hipStream_t stream)
{
  const float* x   = (const float*)d_in[0];
  const float* gw  = (const float*)d_in[1];
  const float* wgu = (const float*)d_in[2];
  const float* wd  = (const float*)d_in[3];
  float* out = (float*)d_out;
  char* ws = (char*)d_ws;

  const size_t off_wgu_t = 0;
  const size_t off_wd_t  = off_wgu_t + (size_t)E_ * GU_ * H_ * 2;
  const size_t off_xb    = off_wd_t  + (size_t)E_ * H_ * I_ * 2;
  const size_t off_act   = off_xb    + (size_t)T_ * H_ * 2;
  const size_t off_ctrl  = off_act   + (size_t)2 * T_ * I_ * 2;
  const size_t need = off_ctrl + 128 + 5 * 65536;
  if (ws_size < need) return;

  u16* wgu_t = (u16*)(ws + off_wgu_t);
  u16* wd_t  = (u16*)(ws + off_wd_t);
  u16* xb    = (u16*)(ws + off_xb);
  u16* act   = (u16*)(ws + off_act);
  u16* y     = (u16*)(ws + off_wgu_t);        // alias: wgu_t dead after gemm1
  float* part_imp = (float*)(ws + off_act);   // alias: act dead until gemm1
  int*   part_cnt = (int*)(ws + off_act + (size_t)NBR_ * 8 * 4);
  char* ctrl = ws + off_ctrl;
  int*   counts  = (int*)(ctrl + 0);
  int*   cursors = (int*)(ctrl + 32);
  int*   offsets = (int*)(ctrl + 64);
  int*   tok_e   = (int*)(ctrl + 128);
  float* tok_w   = (float*)(ctrl + 128 + 1 * 65536);
  int*   rows    = (int*)(ctrl + 128 + 2 * 65536);
  float* wslot   = (float*)(ctrl + 128 + 3 * 65536);
  int*   t2s     = (int*)(ctrl + 128 + 4 * 65536);

  static bool attr_done = false;
  if (!attr_done) {
    hipFuncSetAttribute((const void*)k_gemm1, hipFuncAttributeMaxDynamicSharedMemorySize, 131072);
    hipFuncSetAttribute((const void*)k_gemm2, hipFuncAttributeMaxDynamicSharedMemorySize, 131072);
    attr_done = true;
  }

  hipMemsetAsync(ctrl, 0, 96, stream);
  hipLaunchKernelGGL(k_transpose_all, dim3(11264 + 5632), dim3(256), 0, stream, wgu, wgu_t, wd, wd_t);
  hipLaunchKernelGGL(k_router, dim3(NBR_), dim3(256), 0, stream, x, gw, part_imp, part_cnt, tok_e, tok_w, xb);
  hipLaunchKernelGGL(k_reduce_scan, dim3(1), dim3(512), 0, stream, part_imp, part_cnt, counts, offsets, out);
  hipLaunchKernelGGL(k_scatter, dim3(T_ / 256), dim3(256), 0, stream, tok_e, tok_w, offsets, cursors, rows, wslot, t2s);
  hipLaunchKernelGGL(k_gemm1, dim3(32 * (I_ / 128) * E_), dim3(512), 131072, stream, xb, wgu_t, counts, offsets, rows, wslot, act);
  hipLaunchKernelGGL(k_gemm2, dim3(32 * (H_ / 256) * E_), dim3(512), 131072, stream, act, wd_t, counts, offsets, y);
  hipLaunchKernelGGL(k_combine, dim3((T_ * H_) / (256 * 8)), dim3(256), 0, stream, y, t2s, out);
}